// Round 7
// baseline (137.073 us; speedup 1.0000x reference)
//
#include <hip/hip_runtime.h>

// LIF neuron forward, producer-consumer wave specialization, v2.
// V = leak*V + I; spike = (V >= 1); V -= spike.
// current: [B=8, S=4096, D=1024] f32, membrane: [B, D] f32.
// Outputs concatenated: spikes [B,S,D] then mem_final [B,D], all f32.
//
// r6 evidence (117 us, 1.7 TB/s): consumer issue-bound + LDS latency
// bubbles, producers fine. v2: 2 channels/lane (ds_read_b64 +
// store_dwordx2, interleaved dep chains), one-batch-ahead LDS register
// prefetch, and 16B global_load_lds staging two rows per instruction
// (per-lane global source, linear wave-uniform LDS dest).
//
// Numerics (validated r5/r6, absmax 7.6e-6): forward spike == hard
// threshold exactly in fp32; fp contract(off) pins mul-then-add rounding;
// mem update uses w=v-1 selected by the same compare (bit-identical).

#define LIF_B 8
#define LIF_S 4096
#define LIF_D 1024
#define CHUNK 64                      // time steps per ring half
#define NHALF (LIF_S / CHUNK)         // 64
#define CPB   128                     // channels per block (2 per lane)
#define NBLK  (LIF_B * LIF_D / CPB)   // 64 blocks

__global__ __launch_bounds__(256, 1) void lif_pc2_kernel(
    const float* __restrict__ current,
    const float* __restrict__ membrane,
    float* __restrict__ spikes,
    float* __restrict__ mem_out)
{
    #pragma clang fp contract(off)

    __shared__ float ring[2][CHUNK][CPB];   // 64 KB double buffer

    const int wid  = threadIdx.x >> 6;      // 0 = consumer, 1..3 = producers
    const int lane = threadIdx.x & 63;
    const int blk  = blockIdx.x;            // 0..63
    const int bb   = blk >> 3;              // batch (1024/128 = 8 ch-blocks)
    const int ch0  = (blk & 7) * CPB;

    // global row base for this block: row t starts at gbase + t*LIF_D
    const float* gbase = current + (size_t)bb * LIF_S * LIF_D + ch0;

    // producer lane mapping for fused 2-row loads (16B/lane):
    const int prow = lane >> 5;             // 0/1: which of the two rows
    const int pcol = (lane & 31) * 4;       // float offset within row (16B units)

    // consumer channel pair: c2, c2+1
    const int c2 = lane * 2;
    float2 mem2 = make_float2(0.0f, 0.0f);
    float* outp = spikes + (size_t)bb * LIF_S * LIF_D + ch0 + c2;
    const float2* rring = (const float2*)ring;   // row r of buf: rring[(buf*CHUNK+r)*64 + lane]

    // ---- prologue: producers fill half 0; consumer loads membrane ----
    if (wid != 0) {
        const int p = wid - 1;               // 0..2
        for (int f = p; f < CHUNK / 2; f += 3) {
            const float* src = gbase + (size_t)(2 * f + prow) * LIF_D + pcol;
            auto* ldst = (__attribute__((address_space(3))) unsigned int*)
                         (void*)&ring[0][2 * f][0];
            __builtin_amdgcn_global_load_lds(
                (const __attribute__((address_space(1))) unsigned int*)
                    (const void*)src,
                ldst, 16, 0, 0);
        }
    } else {
        mem2 = *(const float2*)&membrane[bb * LIF_D + ch0 + c2];
    }
    __syncthreads();   // producers drain vmcnt -> half 0 resident

    // ---- main loop: consumer eats half h, producers fill half h+1 ----
    for (int h = 0; h < NHALF; ++h) {
        if (wid != 0) {
            if (h + 1 < NHALF) {
                const int p     = wid - 1;
                const int buf   = (h + 1) & 1;
                const int tbase = (h + 1) * CHUNK;
                for (int f = p; f < CHUNK / 2; f += 3) {
                    const float* src = gbase
                        + (size_t)(tbase + 2 * f + prow) * LIF_D + pcol;
                    auto* ldst = (__attribute__((address_space(3))) unsigned int*)
                                 (void*)&ring[buf][2 * f][0];
                    __builtin_amdgcn_global_load_lds(
                        (const __attribute__((address_space(1))) unsigned int*)
                            (const void*)src,
                        ldst, 16, 0, 0);
                }
            }
        } else {
            const int buf   = h & 1;
            const int tbase = h * CHUNK;
            const float2* rb = rring + (size_t)buf * CHUNK * 64 + lane;

            float2 pre[8], nxt[8];
            #pragma unroll
            for (int j = 0; j < 8; ++j) pre[j] = rb[j * 64];

            for (int r0 = 0; r0 < CHUNK; r0 += 8) {
                if (r0 + 8 < CHUNK) {
                    #pragma unroll
                    for (int j = 0; j < 8; ++j) nxt[j] = rb[(r0 + 8 + j) * 64];
                }
                #pragma unroll
                for (int j = 0; j < 8; ++j) {
                    const float v0 = 0.9f * mem2.x + pre[j].x;  // mul-then-add
                    const float v1 = 0.9f * mem2.y + pre[j].y;
                    const float w0 = v0 - 1.0f;                 // off critical path
                    const float w1 = v1 - 1.0f;
                    const bool  f0 = (v0 >= 1.0f);
                    const bool  f1 = (v1 >= 1.0f);
                    const float s0 = f0 ? 1.0f : 0.0f;
                    const float s1 = f1 ? 1.0f : 0.0f;
                    mem2.x = f0 ? w0 : v0;                      // == v - spike
                    mem2.y = f1 ? w1 : v1;
                    *(float2*)&outp[(size_t)(tbase + r0 + j) * LIF_D]
                        = make_float2(s0, s1);
                }
                #pragma unroll
                for (int j = 0; j < 8; ++j) pre[j] = nxt[j];
            }
        }
        __syncthreads();
    }

    if (wid == 0)
        *(float2*)&mem_out[bb * LIF_D + ch0 + c2] = mem2;
}

extern "C" void kernel_launch(void* const* d_in, const int* in_sizes, int n_in,
                              void* d_out, int out_size, void* d_ws, size_t ws_size,
                              hipStream_t stream) {
    const float* current  = (const float*)d_in[0];   // [8, 4096, 1024]
    const float* membrane = (const float*)d_in[1];   // [8, 1024]

    float* spikes  = (float*)d_out;                                 // [8,4096,1024]
    float* mem_out = (float*)d_out + (size_t)LIF_B * LIF_S * LIF_D; // [8,1024]

    dim3 block(256);                 // 4 waves: 1 consumer + 3 producers
    dim3 grid(NBLK);                 // 64 blocks (128 channels each)

    hipLaunchKernelGGL(lif_pc2_kernel, grid, block, 0, stream,
                       current, membrane, spikes, mem_out);
}

// Round 8
// 96.714 us; speedup vs baseline: 1.4173x; 1.4173x over previous
//
#include <hip/hip_runtime.h>

// LIF neuron forward, 3-stage wave pipeline (v3).
// V = leak*V + I; spike = (V >= 1); V -= spike.
// current: [B=8, S=4096, D=1024] f32, membrane: [B, D] f32.
// Outputs concatenated: spikes [B,S,D] then mem_final [B,D], all f32.
//
// r6 (117us): consumer stalled on global-store addressing + LDS bubbles.
// r7 (137us): 2ch/lane consumer 1.7x better per ch-step, but 64 blocks
// halved chip parallelism -> regression. v3 keeps 128 blocks and makes the
// consumer LDS-only: w0 consumer (immediate-offset ds_read/ds_write only),
// w1 input producer (1KB fused global_load_lds), w2/w3 writers (ds_read_b128
// + global_store_dwordx4) absorb all store latency.
//
// Numerics (validated r5-r7, absmax 7.6e-6): forward spike == hard
// threshold exactly in fp32; fp contract(off) pins mul-then-add rounding.

#define LIF_B 8
#define LIF_S 4096
#define LIF_D 1024
#define CHUNK 64
#define NHALF (LIF_S / CHUNK)   // 64

typedef __attribute__((address_space(3))) unsigned int lds_uint;
typedef const __attribute__((address_space(1))) unsigned int glb_uint;

__global__ __launch_bounds__(256, 1) void lif_pc3_kernel(
    const float* __restrict__ current,
    const float* __restrict__ membrane,
    float* __restrict__ spikes,
    float* __restrict__ mem_out)
{
    #pragma clang fp contract(off)

    __shared__ __align__(16) float in_ring [2][CHUNK][64];   // 32 KB
    __shared__ __align__(16) float out_ring[2][CHUNK][64];   // 32 KB

    const int wid  = threadIdx.x >> 6;   // 0=consumer 1=producer 2,3=writers
    const int lane = threadIdx.x & 63;
    const int blk  = blockIdx.x;         // 0..127
    const int bb   = blk >> 4;           // batch
    const int ch0  = (blk & 15) * 64;

    const float* gbase = current + (size_t)bb * LIF_S * LIF_D + ch0;
    float*       sbase = spikes  + (size_t)bb * LIF_S * LIF_D + ch0;

    // fused 4-row mapping: lane L -> row (L>>4), float col (L&15)*4
    const int prow = lane >> 4;
    const int pcol = (lane & 15) * 4;

    float mem = 0.0f;

    // ---- prologue ----
    if (wid == 1) {
        #pragma unroll
        for (int f = 0; f < CHUNK / 4; ++f) {     // 16 x 1KB loads
            const float* src = gbase + (size_t)(4 * f + prow) * LIF_D + pcol;
            __builtin_amdgcn_global_load_lds(
                (glb_uint*)(const void*)src,
                (lds_uint*)(void*)&in_ring[0][4 * f][0], 16, 0, 0);
        }
    } else if (wid == 0) {
        mem = membrane[bb * LIF_D + ch0 + lane];
    }
    __syncthreads();   // in[0] resident

    // per-lane LDS bases (select per phase by parity)
    const float* ib0 = &in_ring [0][0][lane];
    const float* ib1 = &in_ring [1][0][lane];
    float*       ob0 = &out_ring[0][0][lane];
    float*       ob1 = &out_ring[1][0][lane];

    for (int h = 0; h < NHALF; ++h) {
        if (wid == 0) {
            // ---- consumer: 64 steps, all-immediate LDS addressing ----
            const float* ib = (h & 1) ? ib1 : ib0;
            float*       ob = (h & 1) ? ob1 : ob0;

            float pre[8], nxt[8];
            #pragma unroll
            for (int j = 0; j < 8; ++j) pre[j] = ib[j * 64];

            for (int r0 = 0; r0 < CHUNK; r0 += 8) {
                if (r0 + 8 < CHUNK) {
                    #pragma unroll
                    for (int j = 0; j < 8; ++j) nxt[j] = ib[(r0 + 8 + j) * 64];
                }
                #pragma unroll
                for (int j = 0; j < 8; ++j) {
                    const float v = 0.9f * mem + pre[j];   // mul-then-add
                    const float w = v - 1.0f;              // off critical path
                    const bool  f = (v >= 1.0f);
                    ob[(r0 + j) * 64] = f ? 1.0f : 0.0f;   // spike -> LDS
                    mem = f ? w : v;                       // soft reset
                }
                #pragma unroll
                for (int j = 0; j < 8; ++j) pre[j] = nxt[j];
            }
        } else if (wid == 1) {
            // ---- producer: stage in[h+1] ----
            if (h + 1 < NHALF) {
                const int buf   = (h + 1) & 1;
                const int tbase = (h + 1) * CHUNK;
                #pragma unroll
                for (int f = 0; f < CHUNK / 4; ++f) {
                    const float* src = gbase
                        + (size_t)(tbase + 4 * f + prow) * LIF_D + pcol;
                    __builtin_amdgcn_global_load_lds(
                        (glb_uint*)(const void*)src,
                        (lds_uint*)(void*)&in_ring[buf][4 * f][0], 16, 0, 0);
                }
            }
        } else {
            // ---- writers: flush out[h-1] ----
            if (h >= 1) {
                const int buf   = (h - 1) & 1;
                const int tbase = (h - 1) * CHUNK;
                const float4* o4 = (const float4*)&out_ring[buf][0][0];
                #pragma unroll
                for (int k = 0; k < 8; ++k) {
                    const int f = (wid - 2) + 2 * k;      // 16 groups over 2 waves
                    const float4 vv = o4[f * 64 + lane];
                    const int    t  = tbase + 4 * f + prow;
                    *(float4*)(sbase + (size_t)t * LIF_D + pcol) = vv;
                }
            }
        }
        __syncthreads();
    }

    // ---- epilogue: flush out[NHALF-1]; store membrane ----
    if (wid >= 2) {
        const int buf   = (NHALF - 1) & 1;
        const int tbase = (NHALF - 1) * CHUNK;
        const float4* o4 = (const float4*)&out_ring[buf][0][0];
        #pragma unroll
        for (int k = 0; k < 8; ++k) {
            const int f = (wid - 2) + 2 * k;
            const float4 vv = o4[f * 64 + lane];
            const int    t  = tbase + 4 * f + prow;
            *(float4*)(sbase + (size_t)t * LIF_D + pcol) = vv;
        }
    } else if (wid == 0) {
        mem_out[bb * LIF_D + ch0 + lane] = mem;
    }
}

extern "C" void kernel_launch(void* const* d_in, const int* in_sizes, int n_in,
                              void* d_out, int out_size, void* d_ws, size_t ws_size,
                              hipStream_t stream) {
    const float* current  = (const float*)d_in[0];   // [8, 4096, 1024]
    const float* membrane = (const float*)d_in[1];   // [8, 1024]

    float* spikes  = (float*)d_out;                                 // [8,4096,1024]
    float* mem_out = (float*)d_out + (size_t)LIF_B * LIF_S * LIF_D; // [8,1024]

    dim3 block(256);                      // w0 consumer, w1 producer, w2-3 writers
    dim3 grid(LIF_B * LIF_D / 64);        // 128 blocks (64 channels each)

    hipLaunchKernelGGL(lif_pc3_kernel, grid, block, 0, stream,
                       current, membrane, spikes, mem_out);
}